// Round 2
// baseline (7857.395 us; speedup 1.0000x reference)
//
#include <hip/hip_runtime.h>
#include <math.h>
#include <limits.h>

#define NT 1024
#define BB 48
#define SS 160
#define VV 32000
#define PADTOK 31999
#define EE 16
#define CAP 20000

// ---------------- device globals (scratch, deterministically rewritten) ------
__device__ int      g_pres[32768];
__device__ int      g_rank[32768];
__device__ float    g_nc[CAP][EE];     // node contents (leaves + composites)
__device__ float    g_nrm[CAP];        // max(||leaf||, 1e-8), numpy-exact
__device__ int      g_tc[CAP][3];      // t_c replica (only [0,hwm) ever read)
__device__ unsigned g_pk[CAP];         // created pair keys (c_c membership)
__device__ int      g_tg[CAP][3];      // compacted targets
__device__ float    g_lo[CAP];         // per-target loss
__device__ int      g_T, g_N;
__device__ float    g_sl[4], g_sr[4], g_cb[4];

// numpy pairwise sum over 16 floats: r[j]=p[j]+p[j+8]; ((r0+r1)+(r2+r3))+((r4+r5)+(r6+r7))
__device__ __forceinline__ float np_sum16(const float* p) {
    float r0 = __fadd_rn(p[0], p[8]);
    float r1 = __fadd_rn(p[1], p[9]);
    float r2 = __fadd_rn(p[2], p[10]);
    float r3 = __fadd_rn(p[3], p[11]);
    float r4 = __fadd_rn(p[4], p[12]);
    float r5 = __fadd_rn(p[5], p[13]);
    float r6 = __fadd_rn(p[6], p[14]);
    float r7 = __fadd_rn(p[7], p[15]);
    float a = __fadd_rn(__fadd_rn(r0, r1), __fadd_rn(r2, r3));
    float b = __fadd_rn(__fadd_rn(r4, r5), __fadd_rn(r6, r7));
    return __fadd_rn(a, b);
}

__global__ __launch_bounds__(NT)
void build_kernel(const int* __restrict__ seqs, const float* __restrict__ emb,
                  const float* __restrict__ comp_l, const float* __restrict__ comp_r,
                  const float* __restrict__ cbp)
{
    const int tid  = threadIdx.x;
    const int lane = tid & 63;
    const int wv   = tid >> 6;

    __shared__ int s_idx[BB][SS];
    __shared__ int s_nv[BB], s_ms[BB], s_comp[BB];
    __shared__ int s_L[BB], s_R[BB], s_found[BB];
    __shared__ unsigned s_pkey[BB], s_skey[BB], s_ssorted[BB];
    __shared__ int s_cA[BB], s_cB[BB], s_dst[BB];
    __shared__ int s_f[6 * BB];
    __shared__ unsigned s_tkey[2 * BB], s_tsorted[2 * BB];
    __shared__ int s_found2[2 * BB];
    __shared__ int s_t0[2 * BB], s_t1[2 * BB], s_t2[2 * BB];
    __shared__ int s_ncand, s_kn, s_kcnt, s_mt;
    __shared__ int s_mx, s_adds;
    __shared__ int s_md, s_ncr, s_hwm, s_nleaves;
    __shared__ int s_scan[NT / 64];
    __shared__ float s_sl4[4], s_sr4[4], s_cb4[4];

    // ---------- init: unique(seqs) + rank lookup ----------
    for (int v = tid; v < 32768; v += NT) g_pres[v] = 0;
    __syncthreads();
    for (int i = tid; i < BB * SS; i += NT) g_pres[seqs[i]] = 1;
    __syncthreads();
    int base = tid * 32;
    int c = 0;
    for (int k = 0; k < 32; ++k) { int v = base + k; if (v < VV) c += g_pres[v]; }
    int incl = c;
    for (int off = 1; off < 64; off <<= 1) {
        int t = __shfl_up(incl, off);
        if (lane >= off) incl += t;
    }
    if (lane == 63) s_scan[wv] = incl;
    __syncthreads();
    if (tid == 0) {
        int run = 0;
        for (int w = 0; w < NT / 64; ++w) { int t = s_scan[w]; s_scan[w] = run; run += t; }
        s_nleaves = run - 1;       // total present minus pad token
        s_md = run - 2;            // md = n_leaves - 1
        s_ncr = 0; s_hwm = 0;
    }
    __syncthreads();
    {
        int run = s_scan[wv] + incl - c;
        for (int k = 0; k < 32; ++k) {
            int v = base + k;
            if (v < VV && g_pres[v]) g_rank[v] = run++;
        }
    }
    __syncthreads();
    // leaf vectors
    for (int v = tid; v < VV; v += NT) {
        if (g_pres[v] && v != PADTOK) {
            int r = g_rank[v];
            #pragma unroll
            for (int e = 0; e < EE; ++e) g_nc[r][e] = emb[v * EE + e];
        }
    }
    if (tid < 4) {
        float sl = 1.0f / (1.0f + expf(-comp_l[tid]));
        float sr = 1.0f / (1.0f + expf(-comp_r[tid]));
        s_sl4[tid] = sl; s_sr4[tid] = sr; s_cb4[tid] = cbp[tid];
        g_sl[tid] = sl;  g_sr[tid] = sr;  g_cb[tid] = cbp[tid];
    }
    __syncthreads();
    const int nleaves = s_nleaves;
    for (int l = tid; l < nleaves; l += NT) {
        float p[EE];
        #pragma unroll
        for (int e = 0; e < EE; ++e) { float x = g_nc[l][e]; p[e] = __fmul_rn(x, x); }
        g_nrm[l] = fmaxf(__fsqrt_rn(np_sum16(p)), 1e-8f);
    }
    for (int i = tid; i < BB * SS; i += NT) {
        int tok = seqs[i];
        s_idx[i / SS][i % SS] = (tok == PADTOK) ? -1 : g_rank[tok];
    }
    __syncthreads();
    if (tid < BB) {
        int cnt = 0;
        for (int p = 0; p < SS; ++p) cnt += (s_idx[tid][p] >= 0);
        s_nv[tid] = cnt;
    }
    __syncthreads();

    // ---------- main merge loop: 159 iterations ----------
    for (int it = 0; it < SS - 1; ++it) {
        const int W = SS - it;

        // P1: per-row first-max argmax of adjacent cosine sims (numpy-exact fp)
        for (int row = wv; row < BB; row += NT / 64) {
            int nv = s_nv[row];
            int npairs = nv - 1;
            float best = -INFINITY; int bidx = INT_MAX;
            for (int p = lane; p < npairs; p += 64) {
                int a = s_idx[row][p], b = s_idx[row][p + 1];
                const float* pa = g_nc[a];
                const float* pb = g_nc[b];
                float pr[EE];
                #pragma unroll
                for (int e = 0; e < EE; ++e) pr[e] = __fmul_rn(pa[e], pb[e]);
                float dot = np_sum16(pr);
                float cosv = __fdiv_rn(dot, __fmul_rn(g_nrm[a], g_nrm[b]));
                if (cosv > best) { best = cosv; bidx = p; }
            }
            for (int off = 32; off >= 1; off >>= 1) {
                float ob = __shfl_down(best, off);
                int   oi = __shfl_down(bidx, off);
                if (ob > best || (ob == best && oi < bidx)) { best = ob; bidx = oi; }
            }
            if (lane == 0) {
                s_ms[row] = (bidx == INT_MAX) ? 0 : bidx;
                s_comp[row] = (nv > 1) ? 1 : 0;
            }
        }
        if (tid == 0) { s_mx = INT_MIN; s_adds = 0; }
        if (tid < BB) s_found[tid] = 0;
        if (tid < 2 * BB) s_found2[tid] = 0;
        __syncthreads();

        // P2: candidate pair list in row order (wave 0, ballot compaction)
        if (wv == 0) {
            int flag = (lane < BB) ? s_comp[lane] : 0;
            unsigned long long m = __ballot(flag);
            if (flag) {
                int pos = __popcll(m & ((1ULL << lane) - 1ULL));
                int ms = s_ms[lane];
                int a = s_idx[lane][ms], b = s_idx[lane][ms + 1];
                s_pkey[pos] = ((unsigned)a << 16) | (unsigned)b;
                s_L[pos] = ms; s_R[pos] = ms + 1;
            }
            if (lane == 0) s_ncand = __popcll(m);
        }
        __syncthreads();

        const int ncand = s_ncand;
        // P3: mx over completing rows; pair membership vs c_c; adds count; shift reads
        for (int i = tid; i < BB * W; i += NT) {
            int r = i / W, p = i % W;
            if (s_comp[r]) atomicMax(&s_mx, s_idx[r][p]);
        }
        {
            int ncr = s_ncr;
            for (int e = tid; e < ncr; e += NT) {
                unsigned k = g_pk[e];
                for (int j = 0; j < ncand; ++j)
                    if (s_pkey[j] == k) s_found[j] = 1;
            }
        }
        {
            int hw = s_hwm, loc = 0;
            for (int e = tid; e < hw; e += NT)
                if (g_tc[e][0] != -1 && g_tc[e][1] != -1 && g_tc[e][2] != -1) loc++;
            if (loc) atomicAdd(&s_adds, loc);
        }
        int tmpv[8];
        #pragma unroll
        for (int k = 0; k < 8; ++k) {
            int i = tid + k * NT;
            int r = i / SS, p = i % SS;
            int doit = 0;
            if (i < BB * SS && s_comp[r]) {
                int ms = s_ms[r];
                if (p >= ms && p <= W - 2) doit = 1;
            }
            tmpv[k] = doit ? s_idx[r][p + 1] : 0;
        }
        __syncthreads();

        // P4: wave0 compacts kept (not-in-c_c) pair keys; wave1 builds flat f[]
        if (wv == 0) {
            int flag = (lane < ncand) ? (s_found[lane] == 0) : 0;
            unsigned long long m = __ballot(flag);
            if (flag) {
                int pos = __popcll(m & ((1ULL << lane) - 1ULL));
                s_skey[pos] = s_pkey[lane];
            }
            if (lane == 0) s_kn = __popcll(m);
        } else if (wv == 1) {
            int mx = s_mx;
            for (int i = lane; i < 6 * ncand; i += 64) {
                int seg = i / ncand, j = i - seg * ncand;
                int v;
                switch (seg) {
                    case 0: v = s_L[j]; break;
                    case 1: v = s_L[j] - 1; break;
                    case 2: v = s_R[j]; break;
                    case 3: v = s_R[j]; break;
                    case 4: v = s_L[j]; break;
                    default: { int rn = s_R[j] + 1; v = (rn > mx) ? -1 : rn; } break;
                }
                s_f[i] = v;
            }
        }
        __syncthreads();

        // P5: rank-sort pair keys; build triple keys from f
        const int kn = s_kn;
        if (tid < kn) {
            unsigned ki = s_skey[tid];
            int rk = 0;
            for (int j = 0; j < kn; ++j) {
                unsigned kj = s_skey[j];
                if (kj < ki || (kj == ki && j < tid)) rk++;
            }
            s_ssorted[rk] = ki;
        }
        if (tid >= 64 && tid < 64 + 2 * ncand) {
            int j = tid - 64;
            int x = s_f[3 * j], y = s_f[3 * j + 1], z = s_f[3 * j + 2];
            s_tkey[j] = ((unsigned)(x + 1) << 16) | ((unsigned)(y + 1) << 8) | (unsigned)(z + 1);
        }
        __syncthreads();

        // P6: wave0 dedupes sorted pairs -> register new nodes (c_c append)
        if (wv == 0) {
            int mdold = s_md;
            int ncrold = s_ncr;
            int flag = 0;
            if (lane < kn) {
                unsigned k = s_ssorted[lane];
                flag = (lane == 0) || (k != s_ssorted[lane - 1]);
            }
            unsigned long long m = __ballot(flag);
            int kcnt = __popcll(m);
            if (flag) {
                int pos = __popcll(m & ((1ULL << lane) - 1ULL));
                unsigned k = s_ssorted[lane];
                s_cA[pos] = (int)(k >> 16);
                s_cB[pos] = (int)(k & 0xFFFFu);
                s_dst[pos] = mdold + 1 + pos;
                g_pk[ncrold + pos] = k;
            }
            if (lane == 0) {
                s_kcnt = kcnt;
                s_md = mdold + kcnt;
                s_ncr = ncrold + kcnt;
            }
        }
        __syncthreads();

        // P7: rank-sort triple keys (tid<96) | compose new nodes (tid in [128,128+16k))
        const int mt0 = 2 * ncand;
        const int kcnt = s_kcnt;
        if (tid < mt0) {
            unsigned ki = s_tkey[tid];
            int rk = 0;
            for (int j = 0; j < mt0; ++j) {
                unsigned kj = s_tkey[j];
                if (kj < ki || (kj == ki && j < tid)) rk++;
            }
            s_tsorted[rk] = ki;
        }
        if (kcnt > 0 && tid >= 128 && tid < 128 + kcnt * EE) {
            int i = tid - 128;
            int j = i >> 4, e = i & 15;
            float lv = g_nc[s_cA[j]][e], rv = g_nc[s_cB[j]][e];
            g_nc[s_dst[j]][e] = lv * s_sl4[e & 3] + rv * s_sr4[e & 3] + s_cb4[e & 3];
        }
        __syncthreads();

        // P8: wave0 dedupe-compacts triples (only if src.size > 0, per reference)
        if (wv == 0) {
            if (kcnt == 0) {
                if (lane == 0) s_mt = 0;
            } else {
                int cnt = 0;
                for (int chunk = 0; chunk < 2; ++chunk) {
                    int e = chunk * 64 + lane;
                    int flag = 0;
                    if (e < mt0) {
                        unsigned k = s_tsorted[e];
                        flag = (e == 0) || (k != s_tsorted[e - 1]);
                    }
                    unsigned long long m = __ballot(flag);
                    if (flag) {
                        int pos = cnt + __popcll(m & ((1ULL << lane) - 1ULL));
                        unsigned k = s_tsorted[e];
                        s_t0[pos] = (int)(k >> 16) - 1;
                        s_t1[pos] = (int)((k >> 8) & 0xFFu) - 1;
                        s_t2[pos] = (int)(k & 0xFFu) - 1;
                        if (k == 0u) s_found2[pos] = 1;  // (-1,-1,-1): matches virgin t_c rows
                    }
                    cnt += __popcll(m);
                }
                if (lane == 0) s_mt = cnt;
            }
        }
        __syncthreads();

        // P9: triple membership vs t_c[0:hwm)
        const int mt = s_mt;
        if (mt > 0) {
            int hw = s_hwm;
            for (int e = tid; e < hw; e += NT) {
                int a0 = g_tc[e][0], a1 = g_tc[e][1], a2 = g_tc[e][2];
                for (int j = 0; j < mt; ++j)
                    if (s_t0[j] == a0 && s_t1[j] == a1 && s_t2[j] == a2) s_found2[j] = 1;
            }
        }
        __syncthreads();

        // P10: write kept triples at t_c[adds..] (wave0); apply index shifts (all)
        if (wv == 0 && mt > 0) {
            int adds = s_adds;
            int cnt = 0;
            for (int chunk = 0; chunk < 2; ++chunk) {
                int j = chunk * 64 + lane;
                int flag = (j < mt) ? (s_found2[j] == 0) : 0;
                unsigned long long m = __ballot(flag);
                if (flag) {
                    int pos = adds + cnt + __popcll(m & ((1ULL << lane) - 1ULL));
                    g_tc[pos][0] = s_t0[j];
                    g_tc[pos][1] = s_t1[j];
                    g_tc[pos][2] = s_t2[j];
                }
                cnt += __popcll(m);
            }
            if (lane == 0) { int e = adds + cnt; if (e > s_hwm) s_hwm = e; }
        }
        #pragma unroll
        for (int k = 0; k < 8; ++k) {
            int i = tid + k * NT;
            int r = i / SS, p = i % SS;
            if (i < BB * SS && s_comp[r]) {
                int ms = s_ms[r];
                if (p >= ms && p <= W - 2) s_idx[r][p] = tmpv[k];
            }
        }
        __syncthreads();
        if (tid < BB && s_comp[tid]) s_nv[tid] -= 1;
        __syncthreads();
    }

    // ---------- finalize: compact valid target rows, publish T and N ----------
    {
        int hw = s_hwm;
        int per = (hw + NT - 1) / NT;
        int b2 = tid * per;
        int cnt = 0;
        for (int k = 0; k < per; ++k) {
            int e = b2 + k;
            if (e < hw && g_tc[e][0] != -1 && g_tc[e][1] != -1 && g_tc[e][2] != -1) cnt++;
        }
        int incl2 = cnt;
        for (int off = 1; off < 64; off <<= 1) {
            int t = __shfl_up(incl2, off);
            if (lane >= off) incl2 += t;
        }
        if (lane == 63) s_scan[wv] = incl2;
        __syncthreads();
        if (tid == 0) {
            int run = 0;
            for (int w = 0; w < NT / 64; ++w) { int t = s_scan[w]; s_scan[w] = run; run += t; }
            g_T = run;
            g_N = s_md + 1;
        }
        __syncthreads();
        int off2 = s_scan[wv] + incl2 - cnt;
        for (int k = 0; k < per; ++k) {
            int e = b2 + k;
            if (e < hw && g_tc[e][0] != -1 && g_tc[e][1] != -1 && g_tc[e][2] != -1) {
                g_tg[off2][0] = g_tc[e][0];
                g_tg[off2][1] = g_tc[e][1];
                g_tg[off2][2] = g_tc[e][2];
                off2++;
            }
        }
    }
}

// ---------------- per-target log-softmax loss ----------------
__global__ __launch_bounds__(256)
void loss_kernel()
{
    __shared__ float s_u[EE];
    __shared__ float s_m[256], s_s[256];
    __shared__ float s_xlab;
    const int tid = threadIdx.x;
    const int T = g_T, N = g_N;
    for (int ti = blockIdx.x; ti < T; ti += gridDim.x) {
        int lab = g_tg[ti][0], l = g_tg[ti][1], r = g_tg[ti][2];
        if (tid < EE)
            s_u[tid] = g_nc[l][tid] * g_sl[tid & 3] + g_nc[r][tid] * g_sr[tid & 3] + g_cb[tid & 3];
        __syncthreads();
        float u[EE];
        #pragma unroll
        for (int e = 0; e < EE; ++e) u[e] = s_u[e];
        float m = -INFINITY, s = 0.0f;
        for (int j = tid; j < N; j += 256) {
            const float* pj = g_nc[j];
            float x = 0.f;
            #pragma unroll
            for (int e = 0; e < EE; ++e) x += u[e] * pj[e];
            if (x > m) { s = s * expf(m - x) + 1.0f; m = x; }
            else s += expf(x - m);
            if (j == lab) s_xlab = x;
        }
        s_m[tid] = m; s_s[tid] = s;
        __syncthreads();
        for (int st = 128; st >= 1; st >>= 1) {
            if (tid < st) {
                float m1 = s_m[tid], s1 = s_s[tid];
                float m2 = s_m[tid + st], s2 = s_s[tid + st];
                if (m2 == -INFINITY) { /* nothing */ }
                else if (m2 > m1) { s1 = s1 * expf(m1 - m2) + s2; m1 = m2; }
                else { s1 = s1 + s2 * expf(m2 - m1); }
                s_m[tid] = m1; s_s[tid] = s1;
            }
            __syncthreads();
        }
        if (tid == 0) g_lo[ti] = s_m[0] + logf(s_s[0]) - s_xlab;
        __syncthreads();
    }
}

__global__ __launch_bounds__(256)
void finish_kernel(float* __restrict__ out)
{
    __shared__ float s_p[256];
    const int tid = threadIdx.x;
    const int T = g_T;
    float acc = 0.f;
    for (int i = tid; i < T; i += 256) acc += g_lo[i];
    s_p[tid] = acc;
    __syncthreads();
    for (int st = 128; st >= 1; st >>= 1) {
        if (tid < st) s_p[tid] += s_p[tid + st];
        __syncthreads();
    }
    if (tid == 0) out[0] = (T > 0) ? (s_p[0] / (float)T) : 0.0f;
}

extern "C" void kernel_launch(void* const* d_in, const int* in_sizes, int n_in,
                              void* d_out, int out_size, void* d_ws, size_t ws_size,
                              hipStream_t stream) {
    const int*   seqs = (const int*)d_in[0];
    const float* emb  = (const float*)d_in[1];
    const float* cl   = (const float*)d_in[2];
    const float* cr   = (const float*)d_in[3];
    const float* cb   = (const float*)d_in[4];
    float* out = (float*)d_out;
    build_kernel<<<dim3(1), dim3(NT), 0, stream>>>(seqs, emb, cl, cr, cb);
    loss_kernel<<<dim3(2048), dim3(256), 0, stream>>>();
    finish_kernel<<<dim3(1), dim3(256), 0, stream>>>(out);
}

// Round 3
// 2997.764 us; speedup vs baseline: 2.6211x; 2.6211x over previous
//
#include <hip/hip_runtime.h>
#include <math.h>
#include <limits.h>

#define NT 1024
#define BB 48
#define SS 160
#define VV 32000
#define PADTOK 31999
#define EE 16
#define CAP 20000
#define NWRD 640   // CAP/32 bitset words

// ---------------- device globals (scratch, deterministically rewritten) ------
__device__ int      g_pres[32768];
__device__ int      g_rank[32768];
__device__ float    g_nc[CAP][EE];     // node contents (leaves + composites)
__device__ float    g_nrm[CAP];        // max(||leaf||, 1e-8), numpy-exact
__device__ unsigned g_pk[CAP];         // created pair keys (c_c membership)
__device__ unsigned g_tck[CAP];        // t_c rows as packed keys ((x+1)<<16|(y+1)<<8|(z+1))
__device__ int      g_tg[CAP][3];      // compacted targets
__device__ float    g_lo[CAP];         // per-target loss
__device__ int      g_T, g_N;
__device__ float    g_sl[4], g_sr[4], g_cb[4];

// numpy pairwise sum over 16 floats: r[j]=p[j]+p[j+8]; ((r0+r1)+(r2+r3))+((r4+r5)+(r6+r7))
__device__ __forceinline__ float np_sum16(const float* p) {
    float r0 = __fadd_rn(p[0], p[8]);
    float r1 = __fadd_rn(p[1], p[9]);
    float r2 = __fadd_rn(p[2], p[10]);
    float r3 = __fadd_rn(p[3], p[11]);
    float r4 = __fadd_rn(p[4], p[12]);
    float r5 = __fadd_rn(p[5], p[13]);
    float r6 = __fadd_rn(p[6], p[14]);
    float r7 = __fadd_rn(p[7], p[15]);
    float a = __fadd_rn(__fadd_rn(r0, r1), __fadd_rn(r2, r3));
    float b = __fadd_rn(__fadd_rn(r4, r5), __fadd_rn(r6, r7));
    return __fadd_rn(a, b);
}

__device__ __forceinline__ int key_valid(unsigned k) {
    return (((k >> 16) & 255u) != 0u) && (((k >> 8) & 255u) != 0u) && ((k & 255u) != 0u);
}

__global__ __launch_bounds__(NT)
void build_kernel(const int* __restrict__ seqs, const float* __restrict__ emb,
                  const float* __restrict__ comp_l, const float* __restrict__ comp_r,
                  const float* __restrict__ cbp)
{
    const int tid  = threadIdx.x;
    const int lane = tid & 63;
    const int wv   = tid >> 6;

    __shared__ short    s_idx[BB][SS];
    __shared__ float    s_cos[BB][SS];
    __shared__ int      s_nv[BB], s_ms[BB], s_comp[BB], s_rowmax[BB];
    __shared__ unsigned s_pkey[BB];
    __shared__ int      s_L[BB], s_R[BB], s_found[BB];
    __shared__ unsigned s_skey[BB], s_ssorted[BB];
    __shared__ int      s_cA[BB], s_cB[BB], s_dst[BB];
    __shared__ unsigned s_tkey[2 * BB], s_tsorted[2 * BB], s_stk[2 * BB];
    __shared__ int      s_found2[2 * BB];
    __shared__ float    s_newcos[BB];
    __shared__ unsigned s_tvb[NWRD];   // t_c row-validity bitset
    __shared__ int s_ncand, s_kcnt, s_mt, s_mx, s_adds;
    __shared__ int s_md, s_ncr, s_hwm, s_nleaves;
    __shared__ int s_scan[NT / 64];
    __shared__ float s_sl4[4], s_sr4[4], s_cb4[4];

    // ---------- init: unique(seqs) + rank lookup ----------
    for (int v = tid; v < 32768; v += NT) g_pres[v] = 0;
    if (tid < NWRD) s_tvb[tid] = 0u;
    __syncthreads();
    for (int i = tid; i < BB * SS; i += NT) g_pres[seqs[i]] = 1;
    __syncthreads();
    int base = tid * 32;
    int c = 0;
    for (int k = 0; k < 32; ++k) { int v = base + k; if (v < VV) c += g_pres[v]; }
    int incl = c;
    for (int off = 1; off < 64; off <<= 1) {
        int t = __shfl_up(incl, off);
        if (lane >= off) incl += t;
    }
    if (lane == 63) s_scan[wv] = incl;
    __syncthreads();
    if (tid == 0) {
        int run = 0;
        for (int w = 0; w < NT / 64; ++w) { int t = s_scan[w]; s_scan[w] = run; run += t; }
        s_nleaves = run - 1;       // total present minus pad token
        s_md = run - 2;            // md = n_leaves - 1
        s_ncr = 0; s_hwm = 0;
    }
    __syncthreads();
    {
        int run = s_scan[wv] + incl - c;
        for (int k = 0; k < 32; ++k) {
            int v = base + k;
            if (v < VV && g_pres[v]) g_rank[v] = run++;
        }
    }
    __syncthreads();
    // leaf vectors + s_idx
    for (int v = tid; v < VV; v += NT) {
        if (g_pres[v] && v != PADTOK) {
            int r = g_rank[v];
            #pragma unroll
            for (int e = 0; e < EE; ++e) g_nc[r][e] = emb[v * EE + e];
        }
    }
    if (tid < 4) {
        float sl = 1.0f / (1.0f + expf(-comp_l[tid]));
        float sr = 1.0f / (1.0f + expf(-comp_r[tid]));
        s_sl4[tid] = sl; s_sr4[tid] = sr; s_cb4[tid] = cbp[tid];
        g_sl[tid] = sl;  g_sr[tid] = sr;  g_cb[tid] = cbp[tid];
    }
    for (int i = tid; i < BB * SS; i += NT) {
        int tok = seqs[i];
        s_idx[i / SS][i % SS] = (short)((tok == PADTOK) ? -1 : g_rank[tok]);
    }
    __syncthreads();
    const int nleaves = s_nleaves;
    for (int l = tid; l < nleaves; l += NT) {
        float p[EE];
        #pragma unroll
        for (int e = 0; e < EE; ++e) { float x = g_nc[l][e]; p[e] = __fmul_rn(x, x); }
        g_nrm[l] = fmaxf(__fsqrt_rn(np_sum16(p)), 1e-8f);
    }
    if (tid < BB) {
        int cnt = 0;
        for (int p = 0; p < SS; ++p) cnt += (s_idx[tid][p] >= 0);
        s_nv[tid] = cnt;
    }
    __syncthreads();
    // initial cosine cache (numpy-exact)
    for (int i = tid; i < BB * (SS - 1); i += NT) {
        int r = i / (SS - 1), p = i % (SS - 1);
        if (p < s_nv[r] - 1) {
            int a = s_idx[r][p], b = s_idx[r][p + 1];
            const float* pa = g_nc[a];
            const float* pb = g_nc[b];
            float pr[EE];
            #pragma unroll
            for (int e = 0; e < EE; ++e) pr[e] = __fmul_rn(pa[e], pb[e]);
            s_cos[r][p] = __fdiv_rn(np_sum16(pr), __fmul_rn(g_nrm[a], g_nrm[b]));
        }
    }
    __syncthreads();

    // ---------- main merge loop: 159 iterations, 7 barriers each ----------
    for (int it = 0; it < SS - 1; ++it) {
        const int W = SS - it;

        // ---- A: per-row argmax(cos) [first-max] + row max(idx); zero flags ----
        for (int row = wv; row < BB; row += NT / 64) {
            int nv = s_nv[row];
            int npairs = nv - 1;
            float best = -INFINITY; int bidx = INT_MAX;
            for (int p = lane; p < npairs; p += 64) {
                float cv = s_cos[row][p];
                if (cv > best) { best = cv; bidx = p; }
            }
            int rmax = INT_MIN;
            for (int p = lane; p < W; p += 64) { int v = (int)s_idx[row][p]; if (v > rmax) rmax = v; }
            for (int off = 32; off >= 1; off >>= 1) {
                float ob = __shfl_down(best, off);
                int   oi = __shfl_down(bidx, off);
                int   om = __shfl_down(rmax, off);
                if (ob > best || (ob == best && oi < bidx)) { best = ob; bidx = oi; }
                if (om > rmax) rmax = om;
            }
            if (lane == 0) {
                s_ms[row] = (bidx == INT_MAX) ? 0 : bidx;
                s_comp[row] = (nv > 1) ? 1 : 0;
                s_rowmax[row] = rmax;
            }
        }
        if (tid == 0) s_adds = 0;
        if (tid < BB) s_found[tid] = 0;
        if (tid < 2 * BB) s_found2[tid] = 0;
        __syncthreads();

        // ---- B: wave0 builds candidate list (row order) + mx reduce ----
        if (wv == 0) {
            int flag = (lane < BB) ? s_comp[lane] : 0;
            unsigned long long m = __ballot(flag);
            int rm = flag ? s_rowmax[lane] : INT_MIN;
            if (flag) {
                int pos = __popcll(m & ((1ULL << lane) - 1ULL));
                int ms = s_ms[lane];
                int a = s_idx[lane][ms], b = s_idx[lane][ms + 1];
                s_pkey[pos] = ((unsigned)a << 16) | (unsigned)b;
                s_L[pos] = ms; s_R[pos] = ms + 1;
            }
            for (int off = 32; off >= 1; off >>= 1) { int o = __shfl_down(rm, off); if (o > rm) rm = o; }
            if (lane == 0) { s_ncand = __popcll(m); s_mx = rm; }
        }
        __syncthreads();

        const int ncand = s_ncand;
        // ---- C: pair membership scan | adds popcount | tkey build | cos recompute ----
        {
            int ncr = s_ncr;
            for (int e = tid; e < ncr; e += NT) {
                unsigned k = g_pk[e];
                for (int j = 0; j < ncand; ++j)
                    if (s_pkey[j] == k) s_found[j] = 1;
            }
        }
        {
            int loc = (tid < NWRD) ? __popc(s_tvb[tid]) : 0;
            for (int off = 32; off >= 1; off >>= 1) loc += __shfl_down(loc, off);
            if (lane == 0 && loc) atomicAdd(&s_adds, loc);
        }
        if (tid < 2 * ncand) {
            int comps[3];
            #pragma unroll
            for (int cc = 0; cc < 3; ++cc) {
                int i = 3 * tid + cc;
                int seg = i / ncand, q = i - seg * ncand;
                int v;
                switch (seg) {
                    case 0: v = s_L[q]; break;
                    case 1: v = s_L[q] - 1; break;
                    case 2: v = s_R[q]; break;
                    case 3: v = s_R[q]; break;
                    case 4: v = s_L[q]; break;
                    default: { int rn = s_R[q] + 1; v = (rn > s_mx) ? -1 : rn; } break;
                }
                comps[cc] = v;
            }
            s_tkey[tid] = ((unsigned)(comps[0] + 1) << 16) | ((unsigned)(comps[1] + 1) << 8)
                        | (unsigned)(comps[2] + 1);
        }
        {   // one new cosine per completing row: pair (idx[ms-1], idx[ms+1]), numpy-exact tree
            int row = tid >> 4, e = tid & 15;
            if (tid < BB * 16 && s_comp[row] && s_ms[row] >= 1) {
                int a = s_idx[row][s_ms[row] - 1];
                int b = s_idx[row][s_ms[row] + 1];
                float p = __fmul_rn(g_nc[a][e], g_nc[b][e]);
                p = __fadd_rn(p, __shfl_xor(p, 8, 16));   // r_j = p_j + p_{j+8}
                p = __fadd_rn(p, __shfl_xor(p, 1, 16));   // (r0+r1)...
                p = __fadd_rn(p, __shfl_xor(p, 2, 16));   // ((r0+r1)+(r2+r3))...
                p = __fadd_rn(p, __shfl_xor(p, 4, 16));   // a+b
                if (e == 0) s_newcos[row] = __fdiv_rn(p, __fmul_rn(g_nrm[a], g_nrm[b]));
            }
        }
        __syncthreads();

        // ---- D: wave0: compact+sort+dedupe pairs, register nodes | waves1-2: triple rank-sort ----
        if (wv == 0) {
            int flag = (lane < ncand) ? (s_found[lane] == 0) : 0;
            unsigned long long m = __ballot(flag);
            if (flag) {
                int pos = __popcll(m & ((1ULL << lane) - 1ULL));
                s_skey[pos] = s_pkey[lane];
            }
            int kn = __popcll(m);
            if (lane < kn) {
                unsigned ki = s_skey[lane];
                int rk = 0;
                for (int j = 0; j < kn; ++j) {
                    unsigned kj = s_skey[j];
                    if (kj < ki || (kj == ki && j < lane)) rk++;
                }
                s_ssorted[rk] = ki;
            }
            int mdold = s_md, ncrold = s_ncr;
            int f2 = 0;
            if (lane < kn) {
                unsigned k = s_ssorted[lane];
                f2 = (lane == 0) || (k != s_ssorted[lane - 1]);
            }
            unsigned long long m2 = __ballot(f2);
            int kcnt = __popcll(m2);
            if (f2) {
                int pos = __popcll(m2 & ((1ULL << lane) - 1ULL));
                unsigned k = s_ssorted[lane];
                s_cA[pos] = (int)(k >> 16);
                s_cB[pos] = (int)(k & 0xFFFFu);
                s_dst[pos] = mdold + 1 + pos;
                g_pk[ncrold + pos] = k;
            }
            if (lane == 0) { s_kcnt = kcnt; s_md = mdold + kcnt; s_ncr = ncrold + kcnt; }
        } else if (wv == 1 || wv == 2) {
            int j = tid - 64;
            int mt0 = 2 * ncand;
            if (j < mt0) {
                unsigned ki = s_tkey[j];
                int rk = 0;
                for (int jj = 0; jj < mt0; ++jj) {
                    unsigned kj = s_tkey[jj];
                    if (kj < ki || (kj == ki && jj < j)) rk++;
                }
                s_tsorted[rk] = ki;
            }
        }
        __syncthreads();

        // ---- E: wave0: dedupe-compact triples (sorted) | threads 256+: compose nodes ----
        const int kcnt = s_kcnt;
        if (wv == 0) {
            int mt0 = 2 * ncand;
            if (kcnt == 0) {
                if (lane == 0) s_mt = 0;
            } else {
                int cnt = 0;
                for (int chunk = 0; chunk < 2; ++chunk) {
                    int e = chunk * 64 + lane;
                    int flag = 0;
                    if (e < mt0) {
                        unsigned k = s_tsorted[e];
                        flag = (e == 0) || (k != s_tsorted[e - 1]);
                    }
                    unsigned long long m = __ballot(flag);
                    if (flag) {
                        int pos = cnt + __popcll(m & ((1ULL << lane) - 1ULL));
                        unsigned k = s_tsorted[e];
                        s_stk[pos] = k;
                        if (k == 0u) s_found2[pos] = 1;  // (-1,-1,-1) matches virgin t_c rows
                    }
                    cnt += __popcll(m);
                }
                if (lane == 0) s_mt = cnt;
            }
        } else if (tid >= 256 && tid < 256 + kcnt * EE) {
            int i = tid - 256;
            int j = i >> 4, e = i & 15;
            float lv = g_nc[s_cA[j]][e], rv = g_nc[s_cB[j]][e];
            g_nc[s_dst[j]][e] = lv * s_sl4[e & 3] + rv * s_sr4[e & 3] + s_cb4[e & 3];
        }
        __syncthreads();

        // ---- F: shift reads (regs) + triple membership via binary search ----
        int tmpi[8]; float tmpc[8];
        #pragma unroll
        for (int k = 0; k < 8; ++k) {
            int i = tid + k * NT;
            int r = i / SS, p = i % SS;
            int doit = 0;
            if (i < BB * SS && s_comp[r]) {
                int ms = s_ms[r];
                if (p >= ms && p <= W - 2) doit = 1;
            }
            tmpi[k] = doit ? (int)s_idx[r][p + 1] : 0;
            tmpc[k] = doit ? s_cos[r][p + 1] : 0.0f;
        }
        const int mt = s_mt;
        if (mt > 0) {
            int hw = s_hwm;
            for (int e = tid; e < hw; e += NT) {
                unsigned k = g_tck[e];
                int lo = 0, hi = mt;
                while (lo < hi) { int mid = (lo + hi) >> 1; if (s_stk[mid] < k) lo = mid + 1; else hi = mid; }
                if (lo < mt && s_stk[lo] == k) s_found2[lo] = 1;
            }
        }
        __syncthreads();

        // ---- G: write kept triples + bitset + hwm (wave0); shift writes; newcos; nv-- ----
        if (wv == 0 && mt > 0) {
            int adds = s_adds;
            int cnt = 0;
            for (int chunk = 0; chunk < 2; ++chunk) {
                int j = chunk * 64 + lane;
                int flag = (j < mt) ? (s_found2[j] == 0) : 0;
                unsigned long long m = __ballot(flag);
                if (flag) {
                    int pos = adds + cnt + __popcll(m & ((1ULL << lane) - 1ULL));
                    unsigned k = s_stk[j];
                    g_tck[pos] = k;
                    unsigned w = (unsigned)pos >> 5, bm = 1u << (pos & 31);
                    atomicAnd(&s_tvb[w], ~bm);
                    if (key_valid(k)) atomicOr(&s_tvb[w], bm);
                }
                cnt += __popcll(m);
            }
            if (lane == 0) { int e2 = adds + cnt; if (e2 > s_hwm) s_hwm = e2; }
        }
        #pragma unroll
        for (int k = 0; k < 8; ++k) {
            int i = tid + k * NT;
            int r = i / SS, p = i % SS;
            if (i < BB * SS && s_comp[r]) {
                int ms = s_ms[r];
                if (p >= ms && p <= W - 2) { s_idx[r][p] = (short)tmpi[k]; s_cos[r][p] = tmpc[k]; }
            }
        }
        if (tid < BB && s_comp[tid]) {
            s_nv[tid] -= 1;
            int ms = s_ms[tid];
            if (ms >= 1) s_cos[tid][ms - 1] = s_newcos[tid];
        }
        __syncthreads();
    }

    // ---------- finalize: compact valid target rows, publish T and N ----------
    {
        int hw = s_hwm;
        int per = (hw + NT - 1) / NT;
        int b2 = tid * per;
        int cnt = 0;
        for (int k = 0; k < per; ++k) {
            int e = b2 + k;
            if (e < hw && key_valid(g_tck[e])) cnt++;
        }
        int incl2 = cnt;
        for (int off = 1; off < 64; off <<= 1) {
            int t = __shfl_up(incl2, off);
            if (lane >= off) incl2 += t;
        }
        if (lane == 63) s_scan[wv] = incl2;
        __syncthreads();
        if (tid == 0) {
            int run = 0;
            for (int w = 0; w < NT / 64; ++w) { int t = s_scan[w]; s_scan[w] = run; run += t; }
            g_T = run;
            g_N = s_md + 1;
        }
        __syncthreads();
        int off2 = s_scan[wv] + incl2 - cnt;
        for (int k = 0; k < per; ++k) {
            int e = b2 + k;
            if (e < hw) {
                unsigned kk = g_tck[e];
                if (key_valid(kk)) {
                    g_tg[off2][0] = (int)((kk >> 16) & 255u) - 1;
                    g_tg[off2][1] = (int)((kk >> 8) & 255u) - 1;
                    g_tg[off2][2] = (int)(kk & 255u) - 1;
                    off2++;
                }
            }
        }
    }
}

// ---------------- per-target log-softmax loss ----------------
__global__ __launch_bounds__(256)
void loss_kernel()
{
    __shared__ float s_u[EE];
    __shared__ float s_m[256], s_s[256];
    __shared__ float s_xlab;
    const int tid = threadIdx.x;
    const int T = g_T, N = g_N;
    for (int ti = blockIdx.x; ti < T; ti += gridDim.x) {
        int lab = g_tg[ti][0], l = g_tg[ti][1], r = g_tg[ti][2];
        if (tid < EE)
            s_u[tid] = g_nc[l][tid] * g_sl[tid & 3] + g_nc[r][tid] * g_sr[tid & 3] + g_cb[tid & 3];
        __syncthreads();
        float u[EE];
        #pragma unroll
        for (int e = 0; e < EE; ++e) u[e] = s_u[e];
        float m = -INFINITY, s = 0.0f;
        for (int j = tid; j < N; j += 256) {
            const float* pj = g_nc[j];
            float x = 0.f;
            #pragma unroll
            for (int e = 0; e < EE; ++e) x += u[e] * pj[e];
            if (x > m) { s = s * expf(m - x) + 1.0f; m = x; }
            else s += expf(x - m);
            if (j == lab) s_xlab = x;
        }
        s_m[tid] = m; s_s[tid] = s;
        __syncthreads();
        for (int st = 128; st >= 1; st >>= 1) {
            if (tid < st) {
                float m1 = s_m[tid], s1 = s_s[tid];
                float m2 = s_m[tid + st], s2 = s_s[tid + st];
                if (m2 == -INFINITY) { /* nothing */ }
                else if (m2 > m1) { s1 = s1 * expf(m1 - m2) + s2; m1 = m2; }
                else { s1 = s1 + s2 * expf(m2 - m1); }
                s_m[tid] = m1; s_s[tid] = s1;
            }
            __syncthreads();
        }
        if (tid == 0) g_lo[ti] = s_m[0] + logf(s_s[0]) - s_xlab;
        __syncthreads();
    }
}

__global__ __launch_bounds__(256)
void finish_kernel(float* __restrict__ out)
{
    __shared__ float s_p[256];
    const int tid = threadIdx.x;
    const int T = g_T;
    float acc = 0.f;
    for (int i = tid; i < T; i += 256) acc += g_lo[i];
    s_p[tid] = acc;
    __syncthreads();
    for (int st = 128; st >= 1; st >>= 1) {
        if (tid < st) s_p[tid] += s_p[tid + st];
        __syncthreads();
    }
    if (tid == 0) out[0] = (T > 0) ? (s_p[0] / (float)T) : 0.0f;
}

extern "C" void kernel_launch(void* const* d_in, const int* in_sizes, int n_in,
                              void* d_out, int out_size, void* d_ws, size_t ws_size,
                              hipStream_t stream) {
    const int*   seqs = (const int*)d_in[0];
    const float* emb  = (const float*)d_in[1];
    const float* cl   = (const float*)d_in[2];
    const float* cr   = (const float*)d_in[3];
    const float* cb   = (const float*)d_in[4];
    float* out = (float*)d_out;
    build_kernel<<<dim3(1), dim3(NT), 0, stream>>>(seqs, emb, cl, cr, cb);
    loss_kernel<<<dim3(2048), dim3(256), 0, stream>>>();
    finish_kernel<<<dim3(1), dim3(256), 0, stream>>>(out);
}

// Round 4
// 1613.786 us; speedup vs baseline: 4.8689x; 1.8576x over previous
//
#include <hip/hip_runtime.h>
#include <math.h>
#include <limits.h>

#define NT 1024
#define BB 48
#define SS 160
#define VV 32000
#define PADTOK 31999
#define EE 16
#define CAP 20000
#define NWRD 640          // ceil(CAP/32) bitset words (LDS validity bitset)
#define PHN 32768         // pair-hash entries (pow2)
#define TBW (1 << 19)     // triple bitmap words: 2^24 bits / 32

// ---------------- device globals (scratch, deterministically rewritten) ------
__device__ int      g_pres[32768];
__device__ int      g_rank[32768];
__device__ float    g_nc[CAP][EE];     // node contents (leaves + composites)
__device__ float    g_nrm[CAP];        // max(||leaf||, 1e-8), numpy-exact
__device__ unsigned g_ph[PHN];         // pair-key hash set (0xFFFFFFFF = empty)
__device__ unsigned g_tbm[TBW];        // triple-key membership bitmap (set semantics)
__device__ unsigned g_tck[CAP];        // t_c rows as packed keys ((x+1)<<16|(y+1)<<8|(z+1)); 0 = virgin
__device__ int      g_tg[CAP][3];      // compacted targets
__device__ float    g_lo[CAP];         // per-target loss
__device__ int      g_T, g_N;
__device__ float    g_sl[4], g_sr[4], g_cb[4];

__device__ __forceinline__ unsigned vload(const unsigned* p) {
    return *(const volatile unsigned*)p;   // bypass L1 (coherent with L2 atomics)
}

// numpy pairwise sum over 16 floats: r[j]=p[j]+p[j+8]; ((r0+r1)+(r2+r3))+((r4+r5)+(r6+r7))
__device__ __forceinline__ float np_sum16(const float* p) {
    float r0 = __fadd_rn(p[0], p[8]);
    float r1 = __fadd_rn(p[1], p[9]);
    float r2 = __fadd_rn(p[2], p[10]);
    float r3 = __fadd_rn(p[3], p[11]);
    float r4 = __fadd_rn(p[4], p[12]);
    float r5 = __fadd_rn(p[5], p[13]);
    float r6 = __fadd_rn(p[6], p[14]);
    float r7 = __fadd_rn(p[7], p[15]);
    float a = __fadd_rn(__fadd_rn(r0, r1), __fadd_rn(r2, r3));
    float b = __fadd_rn(__fadd_rn(r4, r5), __fadd_rn(r6, r7));
    return __fadd_rn(a, b);
}

__device__ __forceinline__ int key_valid(unsigned k) {
    return (((k >> 16) & 255u) != 0u) && (((k >> 8) & 255u) != 0u) && ((k & 255u) != 0u);
}

// ---------------- multi-block scratch re-init (every call) ----------------
__global__ __launch_bounds__(256)
void init_kernel()
{
    int i = blockIdx.x * 256 + threadIdx.x;      // grid 2048*256 = 524288 = TBW
    if (i < TBW)   g_tbm[i] = 0u;
    if (i < PHN)   g_ph[i] = 0xFFFFFFFFu;
    if (i < 32768) g_pres[i] = 0;
    if (i < CAP)   g_tck[i] = 0u;
}

__global__ __launch_bounds__(NT)
void build_kernel(const int* __restrict__ seqs, const float* __restrict__ emb,
                  const float* __restrict__ comp_l, const float* __restrict__ comp_r,
                  const float* __restrict__ cbp)
{
    const int tid  = threadIdx.x;
    const int lane = tid & 63;
    const int wv   = tid >> 6;

    __shared__ short    s_idx[BB][SS];
    __shared__ float    s_cos[BB][SS];
    __shared__ int      s_nv[BB], s_ms[BB], s_comp[BB], s_rowmax[BB];
    __shared__ unsigned s_pkey[BB];
    __shared__ int      s_L[BB], s_R[BB], s_found[BB];
    __shared__ unsigned s_skey[BB], s_ssorted[BB];
    __shared__ int      s_cA[BB], s_cB[BB], s_dst[BB];
    __shared__ unsigned s_tkey[2 * BB], s_tsorted[2 * BB], s_stk[2 * BB];
    __shared__ float    s_newcos[BB];
    __shared__ unsigned s_tvb[NWRD];   // t_c row-validity bitset (positional, for adds)
    __shared__ int s_ncand, s_kcnt, s_mx, s_adds;
    __shared__ int s_md, s_hwm, s_nleaves;
    __shared__ int s_scan[NT / 64];
    __shared__ float s_sl4[4], s_sr4[4], s_cb4[4];

    // ---------- init: unique(seqs) + rank lookup ----------
    if (tid < NWRD) s_tvb[tid] = 0u;
    for (int i = tid; i < BB * SS; i += NT) g_pres[seqs[i]] = 1;
    __syncthreads();
    int base = tid * 32;
    int c = 0;
    for (int k = 0; k < 32; ++k) { int v = base + k; if (v < VV) c += g_pres[v]; }
    int incl = c;
    for (int off = 1; off < 64; off <<= 1) {
        int t = __shfl_up(incl, off);
        if (lane >= off) incl += t;
    }
    if (lane == 63) s_scan[wv] = incl;
    __syncthreads();
    if (tid == 0) {
        int run = 0;
        for (int w = 0; w < NT / 64; ++w) { int t = s_scan[w]; s_scan[w] = run; run += t; }
        s_nleaves = run - 1;       // total present minus pad token
        s_md = run - 2;            // md = n_leaves - 1
        s_hwm = 0;
    }
    __syncthreads();
    {
        int run = s_scan[wv] + incl - c;
        for (int k = 0; k < 32; ++k) {
            int v = base + k;
            if (v < VV && g_pres[v]) g_rank[v] = run++;
        }
    }
    __syncthreads();
    // leaf vectors + s_idx
    for (int v = tid; v < VV; v += NT) {
        if (g_pres[v] && v != PADTOK) {
            int r = g_rank[v];
            #pragma unroll
            for (int e = 0; e < EE; ++e) g_nc[r][e] = emb[v * EE + e];
        }
    }
    if (tid < 4) {
        float sl = 1.0f / (1.0f + expf(-comp_l[tid]));
        float sr = 1.0f / (1.0f + expf(-comp_r[tid]));
        s_sl4[tid] = sl; s_sr4[tid] = sr; s_cb4[tid] = cbp[tid];
        g_sl[tid] = sl;  g_sr[tid] = sr;  g_cb[tid] = cbp[tid];
    }
    for (int i = tid; i < BB * SS; i += NT) {
        int tok = seqs[i];
        s_idx[i / SS][i % SS] = (short)((tok == PADTOK) ? -1 : g_rank[tok]);
    }
    __syncthreads();
    const int nleaves = s_nleaves;
    for (int l = tid; l < nleaves; l += NT) {
        float p[EE];
        #pragma unroll
        for (int e = 0; e < EE; ++e) { float x = g_nc[l][e]; p[e] = __fmul_rn(x, x); }
        g_nrm[l] = fmaxf(__fsqrt_rn(np_sum16(p)), 1e-8f);
    }
    if (tid < BB) {
        int cnt = 0;
        for (int p = 0; p < SS; ++p) cnt += (s_idx[tid][p] >= 0);
        s_nv[tid] = cnt;
    }
    __syncthreads();
    // initial cosine cache (numpy-exact)
    for (int i = tid; i < BB * (SS - 1); i += NT) {
        int r = i / (SS - 1), p = i % (SS - 1);
        if (p < s_nv[r] - 1) {
            int a = s_idx[r][p], b = s_idx[r][p + 1];
            const float* pa = g_nc[a];
            const float* pb = g_nc[b];
            float pr[EE];
            #pragma unroll
            for (int e = 0; e < EE; ++e) pr[e] = __fmul_rn(pa[e], pb[e]);
            s_cos[r][p] = __fdiv_rn(np_sum16(pr), __fmul_rn(g_nrm[a], g_nrm[b]));
        }
    }
    __syncthreads();

    // ---------- main merge loop: 159 iterations, 5 barriers each ----------
    for (int it = 0; it < SS - 1; ++it) {
        const int W = SS - it;

        // ---- A: per-row argmax(cos) [first-max] + row value-max ----
        for (int row = wv; row < BB; row += 16) {
            int nv = s_nv[row];
            int npairs = nv - 1;
            float best = -INFINITY; int bidx = INT_MAX;
            for (int p = lane; p < npairs; p += 64) {
                float cv = s_cos[row][p];
                if (cv > best) { best = cv; bidx = p; }
            }
            int rmax = INT_MIN;
            for (int p = lane; p < W; p += 64) { int v = (int)s_idx[row][p]; if (v > rmax) rmax = v; }
            for (int off = 32; off >= 1; off >>= 1) {
                float ob = __shfl_down(best, off);
                int   oi = __shfl_down(bidx, off);
                int   om = __shfl_down(rmax, off);
                if (ob > best || (ob == best && oi < bidx)) { best = ob; bidx = oi; }
                if (om > rmax) rmax = om;
            }
            if (lane == 0) {
                s_ms[row] = (bidx == INT_MAX) ? 0 : bidx;
                s_comp[row] = (nv > 1) ? 1 : 0;
                s_rowmax[row] = rmax;
            }
        }
        if (tid == 0) s_adds = 0;
        __syncthreads();   // bar1

        // ---- B: wave0 candidates+mx | waves1-3 adds popcount | waves4-15 newcos ----
        if (wv == 0) {
            int flag = (lane < BB) ? s_comp[lane] : 0;
            unsigned long long m = __ballot(flag);
            int rm = flag ? s_rowmax[lane] : INT_MIN;
            if (flag) {
                int pos = __popcll(m & ((1ULL << lane) - 1ULL));
                int ms = s_ms[lane];
                int a = s_idx[lane][ms], b = s_idx[lane][ms + 1];
                s_pkey[pos] = ((unsigned)a << 16) | (unsigned)b;
                s_L[pos] = ms; s_R[pos] = ms + 1;
            }
            for (int off = 32; off >= 1; off >>= 1) { int o = __shfl_down(rm, off); if (o > rm) rm = o; }
            if (lane == 0) { s_ncand = __popcll(m); s_mx = rm; }
        } else if (wv <= 3) {
            int loc = 0;
            for (int w = tid - 64; w < NWRD; w += 192) loc += __popc(s_tvb[w]);
            for (int off = 32; off >= 1; off >>= 1) loc += __shfl_down(loc, off);
            if (lane == 0 && loc) atomicAdd(&s_adds, loc);
        } else {
            int i = tid - 256;               // 768 threads: one (row, elem) each
            int row = i >> 4, e = i & 15;
            if (s_comp[row] && s_ms[row] >= 1) {
                int a = (int)s_idx[row][s_ms[row] - 1];
                int b = (int)s_idx[row][s_ms[row] + 1];
                float p = __fmul_rn(g_nc[a][e], g_nc[b][e]);
                p = __fadd_rn(p, __shfl_xor(p, 8, 16));   // r_j = p_j + p_{j+8}
                p = __fadd_rn(p, __shfl_xor(p, 1, 16));
                p = __fadd_rn(p, __shfl_xor(p, 2, 16));
                p = __fadd_rn(p, __shfl_xor(p, 4, 16));
                if (e == 0) s_newcos[row] = __fdiv_rn(p, __fmul_rn(g_nrm[a], g_nrm[b]));
            }
        }
        __syncthreads();   // bar2

        const int ncand = s_ncand;
        // ---- C: wave0 pair-hash probes | waves1-2 tkey build ----
        if (wv == 0) {
            if (lane < ncand) {
                unsigned k = s_pkey[lane];
                unsigned h = (k * 2654435761u) >> 17;
                int found = 0;
                while (true) {
                    unsigned v = vload(&g_ph[h]);
                    if (v == k) { found = 1; break; }
                    if (v == 0xFFFFFFFFu) break;
                    h = (h + 1) & (PHN - 1);
                }
                s_found[lane] = found;
            }
        } else if (wv <= 2) {
            int j = tid - 64;
            if (j < 2 * ncand) {
                int comps[3];
                #pragma unroll
                for (int cc = 0; cc < 3; ++cc) {
                    int i = 3 * j + cc;
                    int seg = i / ncand, q = i - seg * ncand;
                    int v;
                    switch (seg) {
                        case 0: v = s_L[q]; break;
                        case 1: v = s_L[q] - 1; break;
                        case 2: v = s_R[q]; break;
                        case 3: v = s_R[q]; break;
                        case 4: v = s_L[q]; break;
                        default: { int rn = s_R[q] + 1; v = (rn > s_mx) ? -1 : rn; } break;
                    }
                    comps[cc] = v;
                }
                s_tkey[j] = ((unsigned)(comps[0] + 1) << 16) | ((unsigned)(comps[1] + 1) << 8)
                          | (unsigned)(comps[2] + 1);
            }
        }
        __syncthreads();   // bar3

        // ---- D: wave0 pair compact+sort+dedupe+hash-insert+register | waves1-2 triple rank-sort ----
        if (wv == 0) {
            int flag = (lane < ncand) ? (s_found[lane] == 0) : 0;
            unsigned long long m = __ballot(flag);
            if (flag) {
                int pos = __popcll(m & ((1ULL << lane) - 1ULL));
                s_skey[pos] = s_pkey[lane];
            }
            int kn = __popcll(m);
            if (lane < kn) {
                unsigned ki = s_skey[lane];
                int rk = 0;
                for (int j = 0; j < kn; ++j) {
                    unsigned kj = s_skey[j];
                    if (kj < ki || (kj == ki && j < lane)) rk++;
                }
                s_ssorted[rk] = ki;
            }
            int mdold = s_md;
            int f2 = 0;
            if (lane < kn) {
                unsigned k = s_ssorted[lane];
                f2 = (lane == 0) || (k != s_ssorted[lane - 1]);
            }
            unsigned long long m2 = __ballot(f2);
            int kcnt = __popcll(m2);
            if (f2) {
                int pos = __popcll(m2 & ((1ULL << lane) - 1ULL));
                unsigned k = s_ssorted[lane];
                s_cA[pos] = (int)(k >> 16);
                s_cB[pos] = (int)(k & 0xFFFFu);
                s_dst[pos] = mdold + 1 + pos;
                unsigned h = (k * 2654435761u) >> 17;
                while (true) {
                    unsigned prev = atomicCAS(&g_ph[h], 0xFFFFFFFFu, k);
                    if (prev == 0xFFFFFFFFu) break;
                    h = (h + 1) & (PHN - 1);
                }
            }
            if (lane == 0) { s_kcnt = kcnt; s_md = mdold + kcnt; }
        } else if (wv <= 2) {
            int j = tid - 64;
            int mt0 = 2 * ncand;
            if (j < mt0) {
                unsigned ki = s_tkey[j];
                int rk = 0;
                for (int jj = 0; jj < mt0; ++jj) {
                    unsigned kj = s_tkey[jj];
                    if (kj < ki || (kj == ki && jj < j)) rk++;
                }
                s_tsorted[rk] = ki;
            }
        }
        __syncthreads();   // bar4

        // ---- E: wave0 triple dedupe+probe+write | waves1-12 row shifts | waves13-15 compose ----
        const int kcnt = s_kcnt;
        if (wv == 0) {
            if (kcnt > 0) {
                int mt0 = 2 * ncand;
                int cnt = 0;
                #pragma unroll
                for (int chunk = 0; chunk < 2; ++chunk) {
                    int e = chunk * 64 + lane;
                    int flag = 0;
                    if (e < mt0) {
                        unsigned k = s_tsorted[e];
                        flag = (e == 0) || (k != s_tsorted[e - 1]);
                    }
                    unsigned long long m = __ballot(flag);
                    if (flag) {
                        int pos = cnt + __popcll(m & ((1ULL << lane) - 1ULL));
                        s_stk[pos] = s_tsorted[e];
                    }
                    cnt += __popcll(m);
                }
                const int mt = cnt;
                // probes (all BEFORE any bitmap update; key 0 == (-1,-1,-1) matches virgin rows)
                int f0 = 0, f1 = 0;
                {
                    int j = lane;
                    if (j < mt) { unsigned k = s_stk[j]; f0 = (k == 0u) || ((vload(&g_tbm[k >> 5]) >> (k & 31)) & 1u); }
                }
                {
                    int j = 64 + lane;
                    if (j < mt) { unsigned k = s_stk[j]; f1 = (k == 0u) || ((vload(&g_tbm[k >> 5]) >> (k & 31)) & 1u); }
                }
                int adds = s_adds;
                int cnt2 = 0;
                #pragma unroll
                for (int chunk = 0; chunk < 2; ++chunk) {
                    int j = chunk * 64 + lane;
                    int f = chunk ? f1 : f0;
                    int flag = (j < mt) && !f;
                    unsigned long long m = __ballot(flag);
                    if (flag) {
                        int pos = adds + cnt2 + __popcll(m & ((1ULL << lane) - 1ULL));
                        unsigned k = s_stk[j];
                        unsigned old = g_tck[pos];
                        if (old) atomicAnd(&g_tbm[old >> 5], ~(1u << (old & 31)));
                        atomicOr(&g_tbm[k >> 5], 1u << (k & 31));
                        g_tck[pos] = k;
                        int w = pos >> 5; unsigned bm = 1u << (pos & 31);
                        atomicAnd(&s_tvb[w], ~bm);
                        if (key_valid(k)) atomicOr(&s_tvb[w], bm);
                    }
                    cnt2 += __popcll(m);
                }
                if (lane == 0) { int e2 = adds + cnt2; if (e2 > s_hwm) s_hwm = e2; }
            }
        } else if (wv <= 12) {
            for (int sub = 0; sub < 4; ++sub) {
                int row = (wv - 1) * 4 + sub;
                if (s_comp[row]) {
                    int ms = s_ms[row];
                    for (int p = ms + lane; p <= W - 2; p += 64) {
                        short v = s_idx[row][p + 1];
                        float cv = s_cos[row][p + 1];
                        s_idx[row][p] = v;
                        s_cos[row][p] = cv;
                    }
                    if (lane == 0) {
                        s_nv[row] -= 1;
                        if (ms >= 1) s_cos[row][ms - 1] = s_newcos[row];
                    }
                }
            }
        } else {
            for (int i = tid - 832; i < kcnt * EE; i += 192) {
                int j = i >> 4, e = i & 15;
                float lv = g_nc[s_cA[j]][e], rv = g_nc[s_cB[j]][e];
                g_nc[s_dst[j]][e] = lv * s_sl4[e & 3] + rv * s_sr4[e & 3] + s_cb4[e & 3];
            }
        }
        __syncthreads();   // bar5
    }

    // ---------- finalize: compact valid target rows, publish T and N ----------
    {
        int hw = s_hwm;
        int per = (hw + NT - 1) / NT;
        int b2 = tid * per;
        int cnt = 0;
        for (int k = 0; k < per; ++k) {
            int e = b2 + k;
            if (e < hw && key_valid(g_tck[e])) cnt++;
        }
        int incl2 = cnt;
        for (int off = 1; off < 64; off <<= 1) {
            int t = __shfl_up(incl2, off);
            if (lane >= off) incl2 += t;
        }
        if (lane == 63) s_scan[wv] = incl2;
        __syncthreads();
        if (tid == 0) {
            int run = 0;
            for (int w = 0; w < NT / 64; ++w) { int t = s_scan[w]; s_scan[w] = run; run += t; }
            g_T = run;
            g_N = s_md + 1;
        }
        __syncthreads();
        int off2 = s_scan[wv] + incl2 - cnt;
        for (int k = 0; k < per; ++k) {
            int e = b2 + k;
            if (e < hw) {
                unsigned kk = g_tck[e];
                if (key_valid(kk)) {
                    g_tg[off2][0] = (int)((kk >> 16) & 255u) - 1;
                    g_tg[off2][1] = (int)((kk >> 8) & 255u) - 1;
                    g_tg[off2][2] = (int)(kk & 255u) - 1;
                    off2++;
                }
            }
        }
    }
}

// ---------------- per-target log-softmax loss ----------------
__global__ __launch_bounds__(256)
void loss_kernel()
{
    __shared__ float s_u[EE];
    __shared__ float s_m[256], s_s[256];
    __shared__ float s_xlab;
    const int tid = threadIdx.x;
    const int T = g_T, N = g_N;
    for (int ti = blockIdx.x; ti < T; ti += gridDim.x) {
        int lab = g_tg[ti][0], l = g_tg[ti][1], r = g_tg[ti][2];
        if (tid < EE)
            s_u[tid] = g_nc[l][tid] * g_sl[tid & 3] + g_nc[r][tid] * g_sr[tid & 3] + g_cb[tid & 3];
        __syncthreads();
        float u[EE];
        #pragma unroll
        for (int e = 0; e < EE; ++e) u[e] = s_u[e];
        float m = -INFINITY, s = 0.0f;
        for (int j = tid; j < N; j += 256) {
            const float* pj = g_nc[j];
            float x = 0.f;
            #pragma unroll
            for (int e = 0; e < EE; ++e) x += u[e] * pj[e];
            if (x > m) { s = s * expf(m - x) + 1.0f; m = x; }
            else s += expf(x - m);
            if (j == lab) s_xlab = x;
        }
        s_m[tid] = m; s_s[tid] = s;
        __syncthreads();
        for (int st = 128; st >= 1; st >>= 1) {
            if (tid < st) {
                float m1 = s_m[tid], s1 = s_s[tid];
                float m2 = s_m[tid + st], s2 = s_s[tid + st];
                if (m2 == -INFINITY) { /* nothing */ }
                else if (m2 > m1) { s1 = s1 * expf(m1 - m2) + s2; m1 = m2; }
                else { s1 = s1 + s2 * expf(m2 - m1); }
                s_m[tid] = m1; s_s[tid] = s1;
            }
            __syncthreads();
        }
        if (tid == 0) g_lo[ti] = s_m[0] + logf(s_s[0]) - s_xlab;
        __syncthreads();
    }
}

__global__ __launch_bounds__(256)
void finish_kernel(float* __restrict__ out)
{
    __shared__ float s_p[256];
    const int tid = threadIdx.x;
    const int T = g_T;
    float acc = 0.f;
    for (int i = tid; i < T; i += 256) acc += g_lo[i];
    s_p[tid] = acc;
    __syncthreads();
    for (int st = 128; st >= 1; st >>= 1) {
        if (tid < st) s_p[tid] += s_p[tid + st];
        __syncthreads();
    }
    if (tid == 0) out[0] = (T > 0) ? (s_p[0] / (float)T) : 0.0f;
}

extern "C" void kernel_launch(void* const* d_in, const int* in_sizes, int n_in,
                              void* d_out, int out_size, void* d_ws, size_t ws_size,
                              hipStream_t stream) {
    const int*   seqs = (const int*)d_in[0];
    const float* emb  = (const float*)d_in[1];
    const float* cl   = (const float*)d_in[2];
    const float* cr   = (const float*)d_in[3];
    const float* cb   = (const float*)d_in[4];
    float* out = (float*)d_out;
    init_kernel<<<dim3(2048), dim3(256), 0, stream>>>();
    build_kernel<<<dim3(1), dim3(NT), 0, stream>>>(seqs, emb, cl, cr, cb);
    loss_kernel<<<dim3(2048), dim3(256), 0, stream>>>();
    finish_kernel<<<dim3(1), dim3(256), 0, stream>>>(out);
}